// Round 10
// baseline (456.678 us; speedup 1.0000x reference)
//
#include <hip/hip_runtime.h>

// ---------- types ----------
typedef short  s16x8 __attribute__((ext_vector_type(8)));
typedef __bf16 bf16x8 __attribute__((ext_vector_type(8)));
typedef float  fx4   __attribute__((ext_vector_type(4)));
typedef float  fx16  __attribute__((ext_vector_type(16)));
typedef unsigned short u16x4 __attribute__((ext_vector_type(4)));
typedef unsigned int   u32x2 __attribute__((ext_vector_type(2)));
typedef unsigned int   u32x4 __attribute__((ext_vector_type(4)));

__device__ __forceinline__ fx4 mfma_bf16(s16x8 a, s16x8 b, fx4 c) {
  return __builtin_amdgcn_mfma_f32_16x16x32_bf16(
      __builtin_bit_cast(bf16x8, a), __builtin_bit_cast(bf16x8, b), c, 0, 0, 0);
}

__device__ __forceinline__ fx16 mfma32(s16x8 a, s16x8 b, fx16 c) {
  return __builtin_amdgcn_mfma_f32_32x32x16_bf16(
      __builtin_bit_cast(bf16x8, a), __builtin_bit_cast(bf16x8, b), c, 0, 0, 0);
}

__device__ __forceinline__ unsigned short f2bf(float f) {
  unsigned int u = __float_as_uint(f);
  u += 0x7fffu + ((u >> 16) & 1u);   // RNE
  return (unsigned short)(u >> 16);
}

__device__ __forceinline__ float bf2f(unsigned int bits16) {
  return __uint_as_float(bits16 << 16);
}

// packed f32x2 -> bf16x2 (RNE), T12 primitive (no builtin on gfx950)
__device__ __forceinline__ unsigned int cvtpk(float lo, float hi) {
  unsigned int r;
  asm volatile("v_cvt_pk_bf16_f32 %0, %1, %2" : "=v"(r) : "v"(lo), "v"(hi));
  return r;
}

// global -> LDS direct copy, 16B per lane; LDS dest = wave-uniform base + lane*16
__device__ __forceinline__ void glds16(const void* g, void* l) {
  __builtin_amdgcn_global_load_lds(
      (__attribute__((address_space(1))) unsigned int*)g,
      (__attribute__((address_space(3))) unsigned int*)l, 16, 0, 0);
}

// ---------- fp32 -> bf16 conversion ----------
__global__ __launch_bounds__(256) void cvt_kernel(const float* __restrict__ src,
                                                  unsigned short* __restrict__ dst, int n) {
  int nv = n >> 2;
  for (int i = blockIdx.x * blockDim.x + threadIdx.x; i < nv; i += gridDim.x * blockDim.x) {
    fx4 v = ((const fx4*)src)[i];
    u16x4 o;
#pragma unroll
    for (int j = 0; j < 4; ++j) o[j] = f2bf(v[j]);
    ((u16x4*)dst)[i] = o;
  }
}

// ---------- GEMM: C[M,N] = A[M,K] * B[N,K]^T ----------
// r9: 256x128 tile, BK=32, 4 waves (2m x 2n), dbuf LDS 48 KiB, grid (16,32) =
// 512 blocks = 2 blocks/CU -- cross-block overlap fills barrier/vmcnt stalls
// (the mechanism every 1-block/CU schedule variant lacked; r5-r8 all ~64 us).
// Per tile: top {vmcnt(6) [FIFO: retire kt's 6, leave kt+1's 6] ; BAR},
// fence-free body (12 ds_read_b128 + 32 MFMA), bottom {BAR ; stage kt+2 (6)}.
// vmcnt never 0 mid-loop (T4). Unit swizzle u^(row&3) -> uniform 8 lanes/bank
// group on b128 reads (floor). XCD swizzle: XCD owns a 4-row by-stripe
// (A-panels 4MB, L2-resident). Same K-order -> bitwise-identical accumulation.
// OMODE: 0 = f32 out, 1 = bf16 out, 2 = bf16 + per-head RMSNorm (head_dim=128;
// block spans exactly one head: tn = bx*128).
template <int OMODE>
__global__ __launch_bounds__(256, 2) void gemm128(const unsigned short* __restrict__ A,
                                                  const unsigned short* __restrict__ B,
                                                  void* __restrict__ Cv,
                                                  const float* __restrict__ g,
                                                  float postscale,
                                                  int M, int N, int K) {
  __shared__ unsigned short lA[2][256 * 32];
  __shared__ unsigned short lB[2][128 * 32];
  const int tid = threadIdx.x, w = tid >> 6, lane = tid & 63;
  const int lid = lane & 15, grp = lane >> 4;
  const int wr = w >> 1, wc = w & 1;
  // XCD swizzle: lin -> (by, bx); XCD x owns by in {4x..4x+3} x all 16 bx
  const int lin = blockIdx.x + gridDim.x * blockIdx.y;   // gridDim.x == 16
  const int xcd = lin & 7, idx = lin >> 3;               // idx 0..63
  const int by = xcd * 4 + (idx >> 4);
  const int bx = idx & 15;
  const int tm = by * 256, tn = bx * 128;

  auto stageA = [&](int buf, int kt) {
    const int k0 = kt * 32;
#pragma unroll
    for (int i = 0; i < 4; ++i) {
      int c = i * 256 + tid;
      int row = c >> 2, u = c & 3;
      int su = u ^ (row & 3);
      glds16(A + (size_t)(tm + row) * K + k0 + su * 8, &lA[buf][(i * 256 + w * 64) * 8]);
    }
  };
  auto stageB = [&](int buf, int kt) {
    const int k0 = kt * 32;
#pragma unroll
    for (int i = 0; i < 2; ++i) {
      int c = i * 256 + tid;
      int row = c >> 2, u = c & 3;
      int su = u ^ (row & 3);
      glds16(B + (size_t)(tn + row) * K + k0 + su * 8, &lB[buf][(i * 256 + w * 64) * 8]);
    }
  };

  fx4 acc[8][4];
#pragma unroll
  for (int i = 0; i < 8; ++i)
#pragma unroll
    for (int j = 0; j < 4; ++j) acc[i][j] = fx4{0.f, 0.f, 0.f, 0.f};

  // prologue: tile0 (6 issues) -> slot0; tile1 (6) -> slot1
  stageA(0, 0); stageB(0, 0);
  stageA(1, 1); stageB(1, 1);

  const int NT = K >> 5;   // 64
  for (int kt = 0; kt < NT; ++kt) {
    const int cur = kt & 1;
    if (kt + 1 < NT) {
      asm volatile("s_waitcnt vmcnt(6)" ::: "memory");   // kt's 6 retired
    } else {
      asm volatile("s_waitcnt vmcnt(0)" ::: "memory");
    }
    __builtin_amdgcn_s_barrier();
    __builtin_amdgcn_sched_barrier(0);

    const unsigned short* la = &lA[cur][0];
    const unsigned short* lb = &lB[cur][0];

    s16x8 bfr[4], af[8];
#pragma unroll
    for (int ni = 0; ni < 4; ++ni) {
      int row = wc * 64 + ni * 16 + lid;
      int u = grp ^ (row & 3);
      bfr[ni] = *(const s16x8*)&lb[row * 32 + u * 8];
    }
#pragma unroll
    for (int mi = 0; mi < 8; ++mi) {
      int row = wr * 128 + mi * 16 + lid;
      int u = grp ^ (row & 3);
      af[mi] = *(const s16x8*)&la[row * 32 + u * 8];
    }
#pragma unroll
    for (int mi = 0; mi < 8; ++mi)
#pragma unroll
      for (int ni = 0; ni < 4; ++ni)
        acc[mi][ni] = mfma_bf16(af[mi], bfr[ni], acc[mi][ni]);

    __builtin_amdgcn_s_barrier();
    __builtin_amdgcn_sched_barrier(0);
    if (kt + 2 < NT) { stageA(cur, kt + 2); stageB(cur, kt + 2); }
  }

  if constexpr (OMODE == 2) {
    // per-row sum of squares over this block's 128-col head (2 waves: wc pair)
    float* lS = (float*)&lA[0][0];
    float red[8][4];
#pragma unroll
    for (int mi = 0; mi < 8; ++mi)
#pragma unroll
      for (int j = 0; j < 4; ++j) {
        float s = 0.f;
#pragma unroll
        for (int ni = 0; ni < 4; ++ni) { float v = acc[mi][ni][j]; s += v * v; }
#pragma unroll
        for (int m = 1; m <= 8; m <<= 1) s += __shfl_xor(s, m, 64);
        red[mi][j] = s;
      }
    if (lid == 0) {
#pragma unroll
      for (int mi = 0; mi < 8; ++mi)
#pragma unroll
        for (int j = 0; j < 4; ++j)
          lS[w * 128 + mi * 16 + grp * 4 + j] = red[mi][j];
    }
    __syncthreads();
#pragma unroll
    for (int mi = 0; mi < 8; ++mi)
#pragma unroll
      for (int j = 0; j < 4; ++j) {
        float tot = red[mi][j] + lS[(w ^ 1) * 128 + mi * 16 + grp * 4 + j];
        red[mi][j] = rsqrtf(tot * (1.0f / 128.0f) + 1e-5f) * postscale;
      }
#pragma unroll
    for (int ni = 0; ni < 4; ++ni) {
      float gv = g[wc * 64 + ni * 16 + lid];
#pragma unroll
      for (int mi = 0; mi < 8; ++mi)
#pragma unroll
        for (int j = 0; j < 4; ++j)
          acc[mi][ni][j] *= red[mi][j] * gv;
    }
  }

#pragma unroll
  for (int mi = 0; mi < 8; ++mi)
#pragma unroll
    for (int ni = 0; ni < 4; ++ni) {
      const int row = tm + wr * 128 + mi * 16 + grp * 4;
      const int col = tn + wc * 64 + ni * 16 + lid;
#pragma unroll
      for (int j = 0; j < 4; ++j) {
        if constexpr (OMODE >= 1)
          ((unsigned short*)Cv)[(size_t)(row + j) * N + col] = f2bf(acc[mi][ni][j]);
        else
          ((float*)Cv)[(size_t)(row + j) * N + col] = acc[mi][ni][j];
      }
    }
}

// ---------- causal flash attention ----------
// 32x32 MFMA, QBLK=32/wave, KVBLK=64, 8 waves/block; triangle pairing jx->{7-jx,jx};
// T1 XCD swizzle. r9: per-step __syncthreads (vmcnt(0) drain) replaced with
// raw s_barrier + lgkmcnt(0) (publishes ds_writes / retires ds_reads) +
// counted vmcnt(4) at step top (retires only prev step's 2 K-glds; this step's
// 4 loads stay in flight across the barrier -- T4 applied to attn).
__global__ __launch_bounds__(512, 2) void attn_kernel(const unsigned short* __restrict__ Q,
                                                      const unsigned short* __restrict__ Kg,
                                                      const unsigned short* __restrict__ Vg,
                                                      unsigned short* __restrict__ O) {
  const int D = 2048, T = 2048;
  __shared__ unsigned short lK[2][64 * 128];   // XOR-swizzled: unit u stores logical u^(row&7)
  __shared__ unsigned short lVT[2][128 * 64];  // V^T, unit u' = u ^ ((d&7)^((d>>3)&7))

  const int tid = threadIdx.x, w = tid >> 6, lane = tid & 63;
  const int lam = lane & 31, H = lane >> 5;
  const int lin = blockIdx.x + gridDim.x * blockIdx.y;   // gridDim.x == 4
  const int xcd = lin & 7, idx = lin >> 3;               // idx 0..31
  const int bh = xcd * 8 + (idx >> 2);
  const int jx = idx & 3;
  const int b = bh >> 4, h = bh & 15;
  const size_t base = (size_t)b * T * D + (size_t)h * 128;
  const unsigned short* Qp = Q + base;
  const unsigned short* Kp = Kg + base;
  const unsigned short* Vp = Vg + base;

  fx16 zf;
#pragma unroll
  for (int i = 0; i < 16; ++i) zf[i] = 0.f;

  s16x8 va, vb;   // in-flight V stage regs

  for (int pass = 0; pass < 2; ++pass) {
    const int qt = (pass == 0) ? (7 - jx) : jx;
    const int qb = qt * 256;
    const int q0 = qb + w * 32;
    const int q = q0 + lam;
    const int nsteps = qt * 4 + 4;

    s16x8 qf[8];
    {
      const unsigned short* qrow = Qp + (size_t)q * D + H * 8;
#pragma unroll
      for (int s = 0; s < 8; ++s) qf[s] = *(const s16x8*)(qrow + s * 16);
    }

    fx16 o[4] = {zf, zf, zf, zf};
    float mrun = -1e30f, lrun = 0.f;

    auto vloadV = [&](int kt0) {
      int p = tid >> 4, d8 = tid & 15;
      const unsigned short* vp = Vp + (size_t)(kt0 + p * 2) * D + d8 * 8;
      va = *(const s16x8*)vp;
      vb = *(const s16x8*)(vp + D);
    };
    auto vwriteV = [&](int bsel) {
      int p = tid >> 4, d8 = tid & 15;
#pragma unroll
      for (int j = 0; j < 8; ++j) {
        int d = d8 * 8 + j;
        int up = (p >> 2) ^ j ^ (d8 & 7);     // u ^ f(d), f(d)=(d&7)^((d>>3)&7)
        unsigned int word = (unsigned int)(unsigned short)va[j] |
                            ((unsigned int)(unsigned short)vb[j] << 16);
        *(unsigned int*)&lVT[bsel][d * 64 + up * 8 + (p & 3) * 2] = word;
      }
    };
    auto stageK = [&](int bsel, int kt0) {
#pragma unroll
      for (int i = 0; i < 2; ++i) {
        int c = i * 512 + tid;
        int row = c >> 4, u = c & 15;
        int su = u ^ (row & 7);
        glds16(Kp + (size_t)(kt0 + row) * D + su * 8, &lK[bsel][(i * 512 + w * 64) * 8]);
      }
    };

    // prologue: stage step 0 (K glds stay in flight past the barrier)
    vloadV(0);
    stageK(0, 0);
    vwriteV(0);                                      // compiler waits its own vmcnt for va/vb
    asm volatile("s_waitcnt lgkmcnt(0)" ::: "memory");
    __builtin_amdgcn_s_barrier();
    __builtin_amdgcn_sched_barrier(0);

    for (int s = 0; s < nsteps; ++s) {
      const int kt0 = s << 6;
      const int cur = s & 1, nxt = cur ^ 1;

      if (s + 1 < nsteps) {
        vloadV((s + 1) << 6);
        stageK(nxt, (s + 1) << 6);
        // retire prev step's 2 K-glds (oldest); leave this step's 4 in flight
        asm volatile("s_waitcnt vmcnt(4)" ::: "memory");
      } else {
        asm volatile("s_waitcnt vmcnt(0)" ::: "memory");
      }
      __builtin_amdgcn_sched_barrier(0);

      if (kt0 <= q0 + 31) {
        // ---- S^T = mfma32(K, Q)
        fx16 st0 = zf, st1 = zf;
#pragma unroll
        for (int ss = 0; ss < 8; ++ss) {
          int uoff = ((2 * ss + H) ^ (lam & 7)) * 8;
          s16x8 k0 = *(const s16x8*)&lK[cur][lam * 128 + uoff];
          s16x8 k1 = *(const s16x8*)&lK[cur][(32 + lam) * 128 + uoff];
          st0 = mfma32(k0, qf[ss], st0);
          st1 = mfma32(k1, qf[ss], st1);
        }

        // ---- causal mask
        if (kt0 + 63 > q0) {
          const int kb = kt0 + 4 * H;
#pragma unroll
          for (int r = 0; r < 16; ++r) {
            int kv = kb + (r & 3) + 8 * (r >> 2);
            if (kv > q) st0[r] = -1e30f;
            if (kv + 32 > q) st1[r] = -1e30f;
          }
        }

        // ---- online softmax (exp2 domain), T13 defer-max
        float pa = fmaxf(st0[0], st0[1]);
        float pb = fmaxf(st0[2], st0[3]);
#pragma unroll
        for (int r = 4; r < 16; r += 4) {
          pa = fmaxf(fmaxf(pa, st0[r]), st0[r + 1]);
          pb = fmaxf(fmaxf(pb, st0[r + 2]), st0[r + 3]);
        }
#pragma unroll
        for (int r = 0; r < 16; r += 4) {
          pa = fmaxf(fmaxf(pa, st1[r]), st1[r + 1]);
          pb = fmaxf(fmaxf(pb, st1[r + 2]), st1[r + 3]);
        }
        float pmax = fmaxf(pa, pb);
        pmax = fmaxf(pmax, __shfl_xor(pmax, 32, 64));
        if (!__all(pmax <= mrun + 12.f)) {
          float mnew = fmaxf(mrun, pmax);
          float al = exp2f(mrun - mnew);
          mrun = mnew;
          lrun *= al;
#pragma unroll
          for (int r = 0; r < 16; ++r) {
            o[0][r] *= al; o[1][r] *= al; o[2][r] *= al; o[3][r] *= al;
          }
        }
        float lloc = 0.f;
#pragma unroll
        for (int r = 0; r < 16; ++r) { st0[r] = exp2f(st0[r] - mrun); lloc += st0[r]; }
#pragma unroll
        for (int r = 0; r < 16; ++r) { st1[r] = exp2f(st1[r] - mrun); lloc += st1[r]; }
        lrun += lloc;

        // ---- pack P to bf16 pair-words (v_cvt_pk), exchange halves
        unsigned int w0[8], w1[8], w0s[8], w1s[8];
#pragma unroll
        for (int m = 0; m < 8; ++m) {
          w0[m] = cvtpk(st0[2 * m], st0[2 * m + 1]);
          w1[m] = cvtpk(st1[2 * m], st1[2 * m + 1]);
        }
#pragma unroll
        for (int m = 0; m < 8; ++m) {
          w0s[m] = __shfl_xor(w0[m], 32, 64);
          w1s[m] = __shfl_xor(w1[m], 32, 64);
        }

        // ---- PV: O^T += mfma32(V^T_frag, P_frag)
        const bool Hi = (H != 0);
#pragma unroll
        for (int c = 0; c < 4; ++c) {
          union { s16x8 v; unsigned int u[4]; } pbu;
          if (c < 2) {
            const int a = 4 * (c & 1);
            pbu.u[0] = Hi ? w0s[a + 2] : w0[a + 0];
            pbu.u[1] = Hi ? w0s[a + 3] : w0[a + 1];
            pbu.u[2] = Hi ? w0[a + 2] : w0s[a + 0];
            pbu.u[3] = Hi ? w0[a + 3] : w0s[a + 1];
          } else {
            const int a = 4 * (c & 1);
            pbu.u[0] = Hi ? w1s[a + 2] : w1[a + 0];
            pbu.u[1] = Hi ? w1s[a + 3] : w1[a + 1];
            pbu.u[2] = Hi ? w1[a + 2] : w1s[a + 0];
            pbu.u[3] = Hi ? w1[a + 3] : w1s[a + 1];
          }
#pragma unroll
          for (int dt = 0; dt < 4; ++dt) {
            int d = dt * 32 + lam;
            int fd = (lam & 7) ^ ((dt * 4 + (lam >> 3)) & 7);
            s16x8 vf = *(const s16x8*)&lVT[cur][d * 64 + ((2 * c + H) ^ fd) * 8];
            o[dt] = mfma32(vf, pbu.v, o[dt]);
          }
        }
      }

      if (s + 1 < nsteps) vwriteV(nxt);
      asm volatile("s_waitcnt lgkmcnt(0)" ::: "memory");  // ds writes visible, ds reads retired
      __builtin_amdgcn_s_barrier();
      __builtin_amdgcn_sched_barrier(0);
    }

    // ---- epilogue
    lrun += __shfl_xor(lrun, 32, 64);
    float inv = 1.f / lrun;
    unsigned short* orow = O + base + (size_t)q * D;
#pragma unroll
    for (int dt = 0; dt < 4; ++dt)
#pragma unroll
      for (int rq = 0; rq < 4; ++rq) {
        u32x2 uv;
        uv[0] = cvtpk(o[dt][rq * 4 + 0] * inv, o[dt][rq * 4 + 1] * inv);
        uv[1] = cvtpk(o[dt][rq * 4 + 2] * inv, o[dt][rq * 4 + 3] * inv);
        *(u32x2*)(orow + dt * 32 + rq * 8 + H * 4) = uv;
      }
  }
}

// ---------- launch ----------
extern "C" void kernel_launch(void* const* d_in, const int* in_sizes, int n_in,
                              void* d_out, int out_size, void* d_ws, size_t ws_size,
                              hipStream_t stream) {
  (void)in_sizes; (void)n_in; (void)out_size; (void)ws_size;
  const float* x  = (const float*)d_in[0];
  const float* Wq = (const float*)d_in[1];
  const float* Wk = (const float*)d_in[2];
  const float* Wv = (const float*)d_in[3];
  const float* Wo = (const float*)d_in[4];
  const float* gq = (const float*)d_in[5];
  const float* gk = (const float*)d_in[6];
  float* out = (float*)d_out;

  // workspace layout (bytes): peak 136 MB
  char* W = (char*)d_ws;
  unsigned short* xb    = (unsigned short*)(W);                       // 32 MB  x bf16 (later reused for attn out)
  unsigned short* wslot = (unsigned short*)(W + (size_t)33554432);    //  8 MB  current weight bf16
  unsigned short* Qb    = (unsigned short*)(W + (size_t)41943040);    // 32 MB
  unsigned short* Kb    = (unsigned short*)(W + (size_t)75497472);    // 32 MB
  unsigned short* Vb    = (unsigned short*)(W + (size_t)109051904);   // 32 MB
  unsigned short* AO    = xb;                                         // attn out reuses x region

  const dim3 gg(16, 32);   // N/128, M/256 -> 512 blocks = 2/CU
  const float qscale = (float)(0.08838834764831845 * 1.4426950408889634); // hd^-0.5 * log2(e)

  cvt_kernel<<<4096, 256, 0, stream>>>(x, xb, 16777216);

  cvt_kernel<<<4096, 256, 0, stream>>>(Wq, wslot, 4194304);
  gemm128<2><<<gg, 256, 0, stream>>>(xb, wslot, Qb, gq, qscale, 8192, 2048, 2048);
  cvt_kernel<<<4096, 256, 0, stream>>>(Wk, wslot, 4194304);
  gemm128<2><<<gg, 256, 0, stream>>>(xb, wslot, Kb, gk, 1.0f, 8192, 2048, 2048);
  cvt_kernel<<<4096, 256, 0, stream>>>(Wv, wslot, 4194304);
  gemm128<1><<<gg, 256, 0, stream>>>(xb, wslot, Vb, gq, 1.0f, 8192, 2048, 2048);

  attn_kernel<<<dim3(4, 64), 512, 0, stream>>>(Qb, Kb, Vb, AO);

  cvt_kernel<<<4096, 256, 0, stream>>>(Wo, wslot, 4194304);
  gemm128<0><<<gg, 256, 0, stream>>>(AO, wslot, out, gq, 1.0f, 8192, 2048, 2048);
}

// Round 11
// 419.711 us; speedup vs baseline: 1.0881x; 1.0881x over previous
//
#include <hip/hip_runtime.h>

// ---------- types ----------
typedef short  s16x8 __attribute__((ext_vector_type(8)));
typedef __bf16 bf16x8 __attribute__((ext_vector_type(8)));
typedef float  fx4   __attribute__((ext_vector_type(4)));
typedef float  fx16  __attribute__((ext_vector_type(16)));
typedef unsigned short u16x4 __attribute__((ext_vector_type(4)));
typedef unsigned int   u32x2 __attribute__((ext_vector_type(2)));
typedef unsigned int   u32x4 __attribute__((ext_vector_type(4)));

__device__ __forceinline__ fx4 mfma_bf16(s16x8 a, s16x8 b, fx4 c) {
  return __builtin_amdgcn_mfma_f32_16x16x32_bf16(
      __builtin_bit_cast(bf16x8, a), __builtin_bit_cast(bf16x8, b), c, 0, 0, 0);
}

__device__ __forceinline__ fx16 mfma32(s16x8 a, s16x8 b, fx16 c) {
  return __builtin_amdgcn_mfma_f32_32x32x16_bf16(
      __builtin_bit_cast(bf16x8, a), __builtin_bit_cast(bf16x8, b), c, 0, 0, 0);
}

__device__ __forceinline__ unsigned short f2bf(float f) {
  unsigned int u = __float_as_uint(f);
  u += 0x7fffu + ((u >> 16) & 1u);   // RNE
  return (unsigned short)(u >> 16);
}

__device__ __forceinline__ float bf2f(unsigned int bits16) {
  return __uint_as_float(bits16 << 16);
}

// packed f32x2 -> bf16x2 (RNE), T12 primitive (no builtin on gfx950)
__device__ __forceinline__ unsigned int cvtpk(float lo, float hi) {
  unsigned int r;
  asm volatile("v_cvt_pk_bf16_f32 %0, %1, %2" : "=v"(r) : "v"(lo), "v"(hi));
  return r;
}

// global -> LDS direct copy, 16B per lane; LDS dest = wave-uniform base + lane*16
__device__ __forceinline__ void glds16(const void* g, void* l) {
  __builtin_amdgcn_global_load_lds(
      (__attribute__((address_space(1))) unsigned int*)g,
      (__attribute__((address_space(3))) unsigned int*)l, 16, 0, 0);
}

// ---------- fp32 -> bf16 conversion ----------
__global__ __launch_bounds__(256) void cvt_kernel(const float* __restrict__ src,
                                                  unsigned short* __restrict__ dst, int n) {
  int nv = n >> 2;
  for (int i = blockIdx.x * blockDim.x + threadIdx.x; i < nv; i += gridDim.x * blockDim.x) {
    fx4 v = ((const fx4*)src)[i];
    u16x4 o;
#pragma unroll
    for (int j = 0; j < 4; ++j) o[j] = f2bf(v[j]);
    ((u16x4*)dst)[i] = o;
  }
}

// ---------- GEMM: C[M,N] = A[M,K] * B[N,K]^T ----------
// 256x256 tile, BK=64, 8 waves (2m x 4n), dbuf LDS 128 KiB, XOR-swizzled units.
// Empirical-best (r8) FENCE-FREE tile body. Per tile:
//   top:    issue stageA(cur^1, kt+1, A13) ; vmcnt(8) [FIFO: leaves exactly
//           kt+1's 8 stages in flight, drains all of kt's] ; BAR (union visible)
//   body:   24 ds_read_b128 + 64 MFMA, NO setprio / NO sched_barrier / NO
//           intra-tile barriers -> compiler software-pipelines (per-group
//           lgkmcnt), MFMA overlaps LDS service across groups and waves.
//   bottom: BAR (all reads of cur retired) ; issue 6 stages of kt+2
//           (B01,B23 -> B slot cur; A02 -> A rows 0-63/128-191 of cur).
// vmcnt never 0 mid-loop (T4). T1 XCD swizzle (gridDim.x==8, gridDim.y%8==0).
// OMODE: 0 = f32 out, 1 = bf16 out, 2 = bf16 + per-head RMSNorm (head_dim=128)
template <int OMODE>
__global__ __launch_bounds__(512, 2) void gemm256(const unsigned short* __restrict__ A,
                                                  const unsigned short* __restrict__ B,
                                                  void* __restrict__ Cv,
                                                  const float* __restrict__ g,
                                                  float postscale,
                                                  int M, int N, int K) {
  __shared__ unsigned short lA[2][256 * 64];
  __shared__ unsigned short lB[2][256 * 64];
  const int tid = threadIdx.x, w = tid >> 6, lane = tid & 63;
  const int lid = lane & 15, grp = lane >> 4;
  const int wr = w >> 2, wc = w & 3;
  // T1 XCD-aware bijective swizzle (dispatch id -> tile)
  const int lin = blockIdx.x + gridDim.x * blockIdx.y;
  const int xcd = lin & 7, idx = lin >> 3;
  const int bx = idx & 7;                              // gridDim.x == 8
  const int by = xcd * (gridDim.y >> 3) + (idx >> 3);
  const int tm = by * 256, tn = bx * 256;

  auto stageA = [&](int buf, int kt, int ia, int ib) {
    const int k0 = kt * 64;
#pragma unroll
    for (int t = 0; t < 2; ++t) {
      int i = t ? ib : ia;
      int c = i * 512 + tid;
      int row = c >> 3, u = c & 7;
      int su = u ^ (row & 7);
      glds16(A + (size_t)(tm + row) * K + k0 + su * 8, &lA[buf][(i * 512 + w * 64) * 8]);
    }
  };
  auto stageB = [&](int buf, int kt, int ia, int ib) {
    const int k0 = kt * 64;
#pragma unroll
    for (int t = 0; t < 2; ++t) {
      int i = t ? ib : ia;
      int c = i * 512 + tid;
      int row = c >> 3, u = c & 7;
      int su = u ^ (row & 7);
      glds16(B + (size_t)(tn + row) * K + k0 + su * 8, &lB[buf][(i * 512 + w * 64) * 8]);
    }
  };

  fx4 acc[8][4];
#pragma unroll
  for (int i = 0; i < 8; ++i)
#pragma unroll
    for (int j = 0; j < 4; ++j) acc[i][j] = fx4{0.f, 0.f, 0.f, 0.f};

  // prologue: tile0 full (8) -> slot0; tile1 B + A{0,2} (6) -> slot1
  // (tile1's A{1,3} issued at top of kt=0)
  stageA(0, 0, 0, 1); stageA(0, 0, 2, 3);
  stageB(0, 0, 0, 1); stageB(0, 0, 2, 3);
  stageB(1, 1, 0, 1); stageB(1, 1, 2, 3);
  stageA(1, 1, 0, 2);

#define BARX { __builtin_amdgcn_s_barrier(); __builtin_amdgcn_sched_barrier(0); }

  const int NT = K >> 6;
  for (int kt = 0; kt < NT; ++kt) {
    const int cur = kt & 1;

    if (kt + 1 < NT) {
      stageA(cur ^ 1, kt + 1, 1, 3);   // completes kt+1's slot (safe: cur^1 not read this tile)
      asm volatile("s_waitcnt vmcnt(8)" ::: "memory");   // drain kt's 8; kt+1's 8 in flight
    } else {
      asm volatile("s_waitcnt vmcnt(0)" ::: "memory");
    }
    BARX                               // tile kt visible to all waves

    const unsigned short* la = &lA[cur][0];
    const unsigned short* lb = &lB[cur][0];

    // ---- fence-free body: 24 reads + 64 MFMA, compiler pipelines
    s16x8 bfr[4][2], af[8][2];
#pragma unroll
    for (int ni = 0; ni < 4; ++ni)
#pragma unroll
      for (int ks = 0; ks < 2; ++ks) {
        int row = wc * 64 + ni * 16 + lid;
        int u = (ks * 4 + grp) ^ (row & 7);
        bfr[ni][ks] = *(const s16x8*)&lb[row * 64 + u * 8];
      }
#pragma unroll
    for (int mi = 0; mi < 8; ++mi)
#pragma unroll
      for (int ks = 0; ks < 2; ++ks) {
        int row = wr * 128 + mi * 16 + lid;
        int u = (ks * 4 + grp) ^ (row & 7);
        af[mi][ks] = *(const s16x8*)&la[row * 64 + u * 8];
      }
#pragma unroll
    for (int mi = 0; mi < 8; ++mi)
#pragma unroll
      for (int ni = 0; ni < 4; ++ni)
#pragma unroll
        for (int ks = 0; ks < 2; ++ks)
          acc[mi][ni] = mfma_bf16(af[mi][ks], bfr[ni][ks], acc[mi][ni]);

    BARX                               // all waves' reads of slot cur retired
    if (kt + 2 < NT) {                 // overwrite slot cur with tile kt+2
      stageB(cur, kt + 2, 0, 1);
      stageB(cur, kt + 2, 2, 3);
      stageA(cur, kt + 2, 0, 2);
    }
  }
#undef BARX

  float rinv[8][4];
  if constexpr (OMODE == 2) {
    // per-row sum of squares over the 128-col head segment (2 waves: wc pairs)
    float* lS = (float*)&lA[0][0];
    float red[8][4];
#pragma unroll
    for (int mi = 0; mi < 8; ++mi)
#pragma unroll
      for (int j = 0; j < 4; ++j) {
        float s = 0.f;
#pragma unroll
        for (int ni = 0; ni < 4; ++ni) { float v = acc[mi][ni][j]; s += v * v; }
#pragma unroll
        for (int m = 1; m <= 8; m <<= 1) s += __shfl_xor(s, m, 64);
        red[mi][j] = s;
      }
    if (lid == 0) {
#pragma unroll
      for (int mi = 0; mi < 8; ++mi)
#pragma unroll
        for (int j = 0; j < 4; ++j)
          lS[w * 128 + mi * 16 + grp * 4 + j] = red[mi][j];
    }
    __syncthreads();
#pragma unroll
    for (int mi = 0; mi < 8; ++mi)
#pragma unroll
      for (int j = 0; j < 4; ++j) {
        float tot = red[mi][j] + lS[(w ^ 1) * 128 + mi * 16 + grp * 4 + j];
        rinv[mi][j] = rsqrtf(tot * (1.0f / 128.0f) + 1e-5f) * postscale;
      }
#pragma unroll
    for (int ni = 0; ni < 4; ++ni) {
      float gv = g[(wc & 1) * 64 + ni * 16 + lid];
#pragma unroll
      for (int mi = 0; mi < 8; ++mi)
#pragma unroll
        for (int j = 0; j < 4; ++j)
          acc[mi][ni][j] *= rinv[mi][j] * gv;
    }
  }

#pragma unroll
  for (int mi = 0; mi < 8; ++mi)
#pragma unroll
    for (int ni = 0; ni < 4; ++ni) {
      const int row = tm + wr * 128 + mi * 16 + grp * 4;
      const int col = tn + wc * 64 + ni * 16 + lid;
#pragma unroll
      for (int j = 0; j < 4; ++j) {
        if constexpr (OMODE >= 1)
          ((unsigned short*)Cv)[(size_t)(row + j) * N + col] = f2bf(acc[mi][ni][j]);
        else
          ((float*)Cv)[(size_t)(row + j) * N + col] = acc[mi][ni][j];
      }
    }
}

// ---------- causal flash attention ----------
// 32x32 MFMA, QBLK=32/wave, KVBLK=64, 8 waves/block (256-row q-tiles): one K/V
// staging stream shared by 8 waves (halved per-wave staging + halved HBM refetch).
// Triangle pairing over 8 tiles: jx in 0..3 handles {7-jx, jx} -> 36 steps/block.
// T1 XCD swizzle: the 4 jx blocks of a (b,h) + 8 bh share an XCD's L2.
// Double-buffered K/V; V ds_writes after compute (T14 split). One barrier/step.
// S^T = mfma32(K,Q); O^T = mfma32(V^T, P). Q pre-scaled by hd^-0.5*log2(e).
__global__ __launch_bounds__(512, 2) void attn_kernel(const unsigned short* __restrict__ Q,
                                                      const unsigned short* __restrict__ Kg,
                                                      const unsigned short* __restrict__ Vg,
                                                      unsigned short* __restrict__ O) {
  const int D = 2048, T = 2048;
  __shared__ unsigned short lK[2][64 * 128];   // XOR-swizzled: unit u stores logical u^(row&7)
  __shared__ unsigned short lVT[2][128 * 64];  // V^T, unit u' = u ^ ((d&7)^((d>>3)&7))

  const int tid = threadIdx.x, w = tid >> 6, lane = tid & 63;
  const int lam = lane & 31, H = lane >> 5;
  // XCD-aware bijective swizzle: lin -> (bh, jx); XCD owns 8 bh x 4 jx
  const int lin = blockIdx.x + gridDim.x * blockIdx.y;   // gridDim.x == 4
  const int xcd = lin & 7, idx = lin >> 3;               // idx 0..31
  const int bh = xcd * 8 + (idx >> 2);
  const int jx = idx & 3;
  const int b = bh >> 4, h = bh & 15;
  const size_t base = (size_t)b * T * D + (size_t)h * 128;
  const unsigned short* Qp = Q + base;
  const unsigned short* Kp = Kg + base;
  const unsigned short* Vp = Vg + base;

  fx16 zf;
#pragma unroll
  for (int i = 0; i < 16; ++i) zf[i] = 0.f;

  s16x8 va, vb;   // in-flight V stage regs

  for (int pass = 0; pass < 2; ++pass) {
    const int qt = (pass == 0) ? (7 - jx) : jx;
    const int qb = qt * 256;
    const int q0 = qb + w * 32;
    const int q = q0 + lam;
    const int nsteps = qt * 4 + 4;

    s16x8 qf[8];
    {
      const unsigned short* qrow = Qp + (size_t)q * D + H * 8;
#pragma unroll
      for (int s = 0; s < 8; ++s) qf[s] = *(const s16x8*)(qrow + s * 16);
    }

    fx16 o[4] = {zf, zf, zf, zf};
    float mrun = -1e30f, lrun = 0.f;

    auto vloadV = [&](int kt0) {
      int p = tid >> 4, d8 = tid & 15;
      const unsigned short* vp = Vp + (size_t)(kt0 + p * 2) * D + d8 * 8;
      va = *(const s16x8*)vp;
      vb = *(const s16x8*)(vp + D);
    };
    auto vwriteV = [&](int bsel) {
      int p = tid >> 4, d8 = tid & 15;
#pragma unroll
      for (int j = 0; j < 8; ++j) {
        int d = d8 * 8 + j;
        int up = (p >> 2) ^ j ^ (d8 & 7);     // u ^ f(d), f(d)=(d&7)^((d>>3)&7)
        unsigned int word = (unsigned int)(unsigned short)va[j] |
                            ((unsigned int)(unsigned short)vb[j] << 16);
        *(unsigned int*)&lVT[bsel][d * 64 + up * 8 + (p & 3) * 2] = word;
      }
    };
    auto stageK = [&](int bsel, int kt0) {
#pragma unroll
      for (int i = 0; i < 2; ++i) {
        int c = i * 512 + tid;
        int row = c >> 4, u = c & 15;
        int su = u ^ (row & 7);
        glds16(Kp + (size_t)(kt0 + row) * D + su * 8, &lK[bsel][(i * 512 + w * 64) * 8]);
      }
    };

    vloadV(0);
    stageK(0, 0);
    vwriteV(0);
    __syncthreads();

    for (int s = 0; s < nsteps; ++s) {
      const int kt0 = s << 6;
      const int cur = s & 1, nxt = cur ^ 1;

      if (s + 1 < nsteps) {
        vloadV((s + 1) << 6);
        stageK(nxt, (s + 1) << 6);
      }

      if (kt0 <= q0 + 31) {
        // ---- S^T = mfma32(K, Q)
        fx16 st0 = zf, st1 = zf;
#pragma unroll
        for (int ss = 0; ss < 8; ++ss) {
          int uoff = ((2 * ss + H) ^ (lam & 7)) * 8;
          s16x8 k0 = *(const s16x8*)&lK[cur][lam * 128 + uoff];
          s16x8 k1 = *(const s16x8*)&lK[cur][(32 + lam) * 128 + uoff];
          st0 = mfma32(k0, qf[ss], st0);
          st1 = mfma32(k1, qf[ss], st1);
        }

        // ---- causal mask
        if (kt0 + 63 > q0) {
          const int kb = kt0 + 4 * H;
#pragma unroll
          for (int r = 0; r < 16; ++r) {
            int kv = kb + (r & 3) + 8 * (r >> 2);
            if (kv > q) st0[r] = -1e30f;
            if (kv + 32 > q) st1[r] = -1e30f;
          }
        }

        // ---- online softmax (exp2 domain), T13 defer-max; max3-fusable chains
        float pa = fmaxf(st0[0], st0[1]);
        float pb = fmaxf(st0[2], st0[3]);
#pragma unroll
        for (int r = 4; r < 16; r += 4) {
          pa = fmaxf(fmaxf(pa, st0[r]), st0[r + 1]);
          pb = fmaxf(fmaxf(pb, st0[r + 2]), st0[r + 3]);
        }
#pragma unroll
        for (int r = 0; r < 16; r += 4) {
          pa = fmaxf(fmaxf(pa, st1[r]), st1[r + 1]);
          pb = fmaxf(fmaxf(pb, st1[r + 2]), st1[r + 3]);
        }
        float pmax = fmaxf(pa, pb);
        pmax = fmaxf(pmax, __shfl_xor(pmax, 32, 64));
        if (!__all(pmax <= mrun + 12.f)) {
          float mnew = fmaxf(mrun, pmax);
          float al = exp2f(mrun - mnew);
          mrun = mnew;
          lrun *= al;
#pragma unroll
          for (int r = 0; r < 16; ++r) {
            o[0][r] *= al; o[1][r] *= al; o[2][r] *= al; o[3][r] *= al;
          }
        }
        float lloc = 0.f;
#pragma unroll
        for (int r = 0; r < 16; ++r) { st0[r] = exp2f(st0[r] - mrun); lloc += st0[r]; }
#pragma unroll
        for (int r = 0; r < 16; ++r) { st1[r] = exp2f(st1[r] - mrun); lloc += st1[r]; }
        lrun += lloc;

        // ---- pack P to bf16 pair-words (v_cvt_pk), exchange halves
        unsigned int w0[8], w1[8], w0s[8], w1s[8];
#pragma unroll
        for (int m = 0; m < 8; ++m) {
          w0[m] = cvtpk(st0[2 * m], st0[2 * m + 1]);
          w1[m] = cvtpk(st1[2 * m], st1[2 * m + 1]);
        }
#pragma unroll
        for (int m = 0; m < 8; ++m) {
          w0s[m] = __shfl_xor(w0[m], 32, 64);
          w1s[m] = __shfl_xor(w1[m], 32, 64);
        }

        // ---- PV: O^T += mfma32(V^T_frag, P_frag)
        const bool Hi = (H != 0);
#pragma unroll
        for (int c = 0; c < 4; ++c) {
          union { s16x8 v; unsigned int u[4]; } pbu;
          if (c < 2) {
            const int a = 4 * (c & 1);
            pbu.u[0] = Hi ? w0s[a + 2] : w0[a + 0];
            pbu.u[1] = Hi ? w0s[a + 3] : w0[a + 1];
            pbu.u[2] = Hi ? w0[a + 2] : w0s[a + 0];
            pbu.u[3] = Hi ? w0[a + 3] : w0s[a + 1];
          } else {
            const int a = 4 * (c & 1);
            pbu.u[0] = Hi ? w1s[a + 2] : w1[a + 0];
            pbu.u[1] = Hi ? w1s[a + 3] : w1[a + 1];
            pbu.u[2] = Hi ? w1[a + 2] : w1s[a + 0];
            pbu.u[3] = Hi ? w1[a + 3] : w1s[a + 1];
          }
#pragma unroll
          for (int dt = 0; dt < 4; ++dt) {
            int d = dt * 32 + lam;
            int fd = (lam & 7) ^ ((dt * 4 + (lam >> 3)) & 7);
            s16x8 vf = *(const s16x8*)&lVT[cur][d * 64 + ((2 * c + H) ^ fd) * 8];
            o[dt] = mfma32(vf, pbu.v, o[dt]);
          }
        }
      }

      if (s + 1 < nsteps) vwriteV(nxt);
      __syncthreads();
    }

    // ---- epilogue
    lrun += __shfl_xor(lrun, 32, 64);
    float inv = 1.f / lrun;
    unsigned short* orow = O + base + (size_t)q * D;
#pragma unroll
    for (int dt = 0; dt < 4; ++dt)
#pragma unroll
      for (int rq = 0; rq < 4; ++rq) {
        u32x2 uv;
        uv[0] = cvtpk(o[dt][rq * 4 + 0] * inv, o[dt][rq * 4 + 1] * inv);
        uv[1] = cvtpk(o[dt][rq * 4 + 2] * inv, o[dt][rq * 4 + 3] * inv);
        *(u32x2*)(orow + dt * 32 + rq * 8 + H * 4) = uv;
      }
  }
}

// ---------- launch ----------
extern "C" void kernel_launch(void* const* d_in, const int* in_sizes, int n_in,
                              void* d_out, int out_size, void* d_ws, size_t ws_size,
                              hipStream_t stream) {
  (void)in_sizes; (void)n_in; (void)out_size; (void)ws_size;
  const float* x  = (const float*)d_in[0];
  const float* Wq = (const float*)d_in[1];
  const float* Wk = (const float*)d_in[2];
  const float* Wv = (const float*)d_in[3];
  const float* Wo = (const float*)d_in[4];
  const float* gq = (const float*)d_in[5];
  const float* gk = (const float*)d_in[6];
  float* out = (float*)d_out;

  // workspace layout (bytes): peak 136 MB
  char* W = (char*)d_ws;
  unsigned short* xb    = (unsigned short*)(W);                       // 32 MB  x bf16 (later reused for attn out)
  unsigned short* wslot = (unsigned short*)(W + (size_t)33554432);    //  8 MB  current weight bf16
  unsigned short* Qb    = (unsigned short*)(W + (size_t)41943040);    // 32 MB
  unsigned short* Kb    = (unsigned short*)(W + (size_t)75497472);    // 32 MB
  unsigned short* Vb    = (unsigned short*)(W + (size_t)109051904);   // 32 MB
  unsigned short* AO    = xb;                                         // attn out reuses x region

  const dim3 gg(8, 32);   // N/256, M/256
  const float qscale = (float)(0.08838834764831845 * 1.4426950408889634); // hd^-0.5 * log2(e)

  cvt_kernel<<<4096, 256, 0, stream>>>(x, xb, 16777216);

  cvt_kernel<<<4096, 256, 0, stream>>>(Wq, wslot, 4194304);
  gemm256<2><<<gg, 512, 0, stream>>>(xb, wslot, Qb, gq, qscale, 8192, 2048, 2048);
  cvt_kernel<<<4096, 256, 0, stream>>>(Wk, wslot, 4194304);
  gemm256<2><<<gg, 512, 0, stream>>>(xb, wslot, Kb, gk, 1.0f, 8192, 2048, 2048);
  cvt_kernel<<<4096, 256, 0, stream>>>(Wv, wslot, 4194304);
  gemm256<1><<<gg, 512, 0, stream>>>(xb, wslot, Vb, gq, 1.0f, 8192, 2048, 2048);

  attn_kernel<<<dim3(4, 64), 512, 0, stream>>>(Qb, Kb, Vb, AO);

  cvt_kernel<<<4096, 256, 0, stream>>>(Wo, wslot, 4194304);
  gemm256<0><<<gg, 512, 0, stream>>>(AO, wslot, out, gq, 1.0f, 8192, 2048, 2048);
}